// Round 15
// baseline (347.884 us; speedup 1.0000x reference)
//
#include <hip/hip_runtime.h>
#include <hip/hip_bf16.h>
#include <stdint.h>

typedef __bf16 bf16_t;
typedef __bf16 bf16x8 __attribute__((ext_vector_type(8)));
typedef float  f32x4  __attribute__((ext_vector_type(4)));

#define MFMA(a, b, c) __builtin_amdgcn_mfma_f32_16x16x32_bf16((a), (b), (c), 0, 0, 0)

// ---- K1 (R13-validated): both linears as one tiled MFMA GEMM
__global__ __launch_bounds__(256) void k_lin2(
    const float* __restrict__ h, const float* __restrict__ Wi,
    const float* __restrict__ bi, const float* __restrict__ Wj,
    const float* __restrict__ bj, bf16_t* __restrict__ ui,
    bf16_t* __restrict__ vj) {
  int m0 = blockIdx.x * 64;
  int which = blockIdx.y;
  const float* W = which ? Wj : Wi;
  const float* bias = which ? bj : bi;
  bf16_t* out = which ? vj : ui;
  __shared__ bf16_t Al[64][136];   // 17408 B
  __shared__ bf16_t Bl[128][136];  // 34816 B
  int w = threadIdx.x >> 6, ln = threadIdx.x & 63;
  int wr = (w >> 1) * 32, wc = (w & 1) * 64;
  int lr = ln & 15, hi8 = (ln >> 4) * 8, rb = (ln >> 4) * 4;
  f32x4 acc[2][4] = {};
  for (int kc0 = 0; kc0 < 1024; kc0 += 128) {
    __syncthreads();  // prev chunk's MFMA reads done
    for (int c = threadIdx.x; c < 64 * 16; c += 256) {
      int row = c >> 4, col = (c & 15) * 8;
      const float* src = &h[(size_t)(m0 + row) * 1024 + kc0 + col];
      f32x4 a = *(const f32x4*)src, b2 = *(const f32x4*)(src + 4);
      bf16x8 o;
#pragma unroll
      for (int e = 0; e < 4; e++) {
        o[e] = (bf16_t)a[e];
        o[e + 4] = (bf16_t)b2[e];
      }
      *(bf16x8*)&Al[row][col] = o;
    }
    for (int c = threadIdx.x; c < 128 * 16; c += 256) {
      int row = c >> 4, col = (c & 15) * 8;
      const float* src = &W[(size_t)row * 1024 + kc0 + col];
      f32x4 a = *(const f32x4*)src, b2 = *(const f32x4*)(src + 4);
      bf16x8 o;
#pragma unroll
      for (int e = 0; e < 4; e++) {
        o[e] = (bf16_t)a[e];
        o[e + 4] = (bf16_t)b2[e];
      }
      *(bf16x8*)&Bl[row][col] = o;
    }
    __syncthreads();  // tiles visible
#pragma unroll
    for (int kc = 0; kc < 128; kc += 32) {
      bf16x8 a0 = *(bf16x8*)&Al[wr + lr][kc + hi8];
      bf16x8 a1 = *(bf16x8*)&Al[wr + 16 + lr][kc + hi8];
#pragma unroll
      for (int fn = 0; fn < 4; fn++) {
        bf16x8 bv = *(bf16x8*)&Bl[wc + fn * 16 + lr][kc + hi8];
        acc[0][fn] = MFMA(a0, bv, acc[0][fn]);
        acc[1][fn] = MFMA(a1, bv, acc[1][fn]);
      }
    }
  }
#pragma unroll
  for (int fm = 0; fm < 2; fm++)
#pragma unroll
    for (int fn = 0; fn < 4; fn++) {
      int col = wc + fn * 16 + lr;
      float bb = bias[col];
#pragma unroll
      for (int r = 0; r < 4; r++) {
        int row = m0 + wr + fm * 16 + rb + r;
        out[row * 128 + col] = (bf16_t)(acc[fm][fn][r] + bb);
      }
    }
}

// ------------------------------------------------- K2a: W[i][j][k]->Wt[k][j][i]
__global__ __launch_bounds__(256) void k_wt(const float* __restrict__ W,
                                            bf16_t* __restrict__ Wt) {
  int j = blockIdx.x;
  int i0 = blockIdx.y * 32, k0 = blockIdx.z * 32;
  __shared__ float tile[32][33];
  int tx = threadIdx.x & 31, ty = threadIdx.x >> 5;  // ty 0..7
#pragma unroll
  for (int r = 0; r < 4; r++) {
    int ii = ty + r * 8;
    tile[ii][tx] = W[(size_t)(i0 + ii) * 16384 + j * 128 + (k0 + tx)];
  }
  __syncthreads();
#pragma unroll
  for (int r = 0; r < 4; r++) {
    int kk = ty + r * 8;
    Wt[(size_t)(k0 + kk) * 16384 + j * 128 + (i0 + tx)] = (bf16_t)tile[tx][kk];
  }
}

// -------- K2b (R3-validated): mix_w -> Wc2[tap][wrh][kc][fm][ln][e]
__global__ __launch_bounds__(256) void k_wc(const float* __restrict__ mw,
                                            bf16_t* __restrict__ Wc2) {
  int idx = blockIdx.x * 256 + threadIdx.x;
  if (idx < 147456) {
    int e = idx & 7, ln = (idx >> 3) & 63, fm = (idx >> 9) & 3;
    int kc = (idx >> 11) & 3, wrh = (idx >> 13) & 1, tap = idx >> 14;
    int oc = wrh * 64 + fm * 16 + (ln & 15);
    int ic = kc * 32 + (ln >> 4) * 8 + e;
    Wc2[idx] = (bf16_t)mw[oc * 1152 + ic * 9 + tap];
  }
}

// -------- K2c (R3-validated): out_w -> Wo2[wrh][kc][fm][ln][e]
__global__ __launch_bounds__(256) void k_wo(const float* __restrict__ ow,
                                            bf16_t* __restrict__ Wo2) {
  int idx = blockIdx.x * 256 + threadIdx.x;
  if (idx < 16384) {
    int e = idx & 7, ln = (idx >> 3) & 63, fm = (idx >> 9) & 3;
    int kc = (idx >> 11) & 3, wrh = (idx >> 13) & 1;
    int oc2 = wrh * 64 + fm * 16 + (ln & 15);
    int mc = kc * 32 + (ln >> 4) * 8 + e;
    Wo2[idx] = (bf16_t)ow[oc2 * 128 + mc];
  }
}

// ------------------- K3: t[bl][k*128+j] = sum_i ui[bl][i] * Wt[k][j][i]  (GEMM)
__global__ __launch_bounds__(256) void k_tgemm(const bf16_t* __restrict__ A,
                                               const bf16_t* __restrict__ Bt,
                                               bf16_t* __restrict__ T) {
  int m0 = blockIdx.x * 64;  // bl
  int n0 = blockIdx.y * 64;  // (k,j)
  __shared__ bf16_t Al[64][136], Bl[64][136];
  for (int c = threadIdx.x; c < 64 * 16; c += 256) {
    int row = c >> 4, col = (c & 15) * 8;
    *(uint4*)&Al[row][col] = *(const uint4*)&A[(size_t)(m0 + row) * 128 + col];
    *(uint4*)&Bl[row][col] = *(const uint4*)&Bt[(size_t)(n0 + row) * 128 + col];
  }
  __syncthreads();
  int w = threadIdx.x >> 6, ln = threadIdx.x & 63;
  int wr = (w >> 1) * 32, wc = (w & 1) * 32;
  int lr = ln & 15, hi8 = (ln >> 4) * 8, rb = (ln >> 4) * 4;
  f32x4 acc[2][2] = {};
#pragma unroll
  for (int kc = 0; kc < 128; kc += 32) {
    bf16x8 a0 = *(bf16x8*)&Al[wr + lr][kc + hi8];
    bf16x8 a1 = *(bf16x8*)&Al[wr + 16 + lr][kc + hi8];
    bf16x8 b0 = *(bf16x8*)&Bl[wc + lr][kc + hi8];
    bf16x8 b1 = *(bf16x8*)&Bl[wc + 16 + lr][kc + hi8];
    acc[0][0] = MFMA(a0, b0, acc[0][0]);
    acc[0][1] = MFMA(a0, b1, acc[0][1]);
    acc[1][0] = MFMA(a1, b0, acc[1][0]);
    acc[1][1] = MFMA(a1, b1, acc[1][1]);
  }
#pragma unroll
  for (int fm = 0; fm < 2; fm++)
#pragma unroll
    for (int fn = 0; fn < 2; fn++) {
      int col = n0 + wc + fn * 16 + lr;
#pragma unroll
      for (int r = 0; r < 4; r++) {
        int row = m0 + wr + fm * 16 + rb + r;
        T[(size_t)row * 16384 + col] = (bf16_t)acc[fm][fn][r];
      }
    }
}

// ------- K4 (R6-validated): feat + fused deterministic norm partial sums
__global__ __launch_bounds__(256) void k_feat(const bf16_t* __restrict__ T,
                                              const bf16_t* __restrict__ Vb,
                                              bf16_t* __restrict__ F,
                                              float* __restrict__ part) {
  int bl = blockIdx.x;
  int b = bl / 384;
  __shared__ __align__(16) char sm[52224];
  bf16_t (*Tl)[136] = (bf16_t(*)[136])(sm);          // 34816
  bf16_t (*Fb)[136] = (bf16_t(*)[136])(sm + 34816);  // 17408
  float* rs = (float*)(sm);                          // overlay after MFMAs
  float* rq = (float*)(sm + 8192);
  const bf16_t* tsrc = T + (size_t)bl * 16384;
  for (int c = threadIdx.x; c < 128 * 16; c += 256) {
    int row = c >> 4, col = (c & 15) * 8;
    *(uint4*)&Tl[row][col] = *(const uint4*)&tsrc[row * 128 + col];
  }
  __syncthreads();
  int w = threadIdx.x >> 6, ln = threadIdx.x & 63;
  int wr = (w >> 1) * 64, wc = (w & 1) * 32;
  int lr = ln & 15, g = ln >> 4, hi8 = g * 8, rb = g * 4;
  size_t base = (size_t)bl * 384 * 128;
  float s8[8] = {}, q8[8] = {};
  int col8 = threadIdx.x & 15;
  for (int mt = 0; mt < 6; mt++) {
    bf16x8 vf[2][4];
#pragma unroll
    for (int fn = 0; fn < 2; fn++)
#pragma unroll
      for (int kc = 0; kc < 4; kc++) {
        int m = mt * 64 + wc + fn * 16 + lr;
        vf[fn][kc] = *(const bf16x8*)&Vb[(size_t)(b * 384 + m) * 128 +
                                         kc * 32 + hi8];
      }
    f32x4 acc[4][2] = {};
#pragma unroll
    for (int kc = 0; kc < 4; kc++) {
#pragma unroll
      for (int fm = 0; fm < 4; fm++) {
        bf16x8 av = *(bf16x8*)&Tl[wr + fm * 16 + lr][kc * 32 + hi8];
        acc[fm][0] = MFMA(av, vf[0][kc], acc[fm][0]);
        acc[fm][1] = MFMA(av, vf[1][kc], acc[fm][1]);
      }
    }
    __syncthreads();  // prev copy-out done: Fb overwrite safe
    union {
      bf16_t h[4];
      uint2 u;
    } pk;
#pragma unroll
    for (int fm = 0; fm < 4; fm++)
#pragma unroll
      for (int fn = 0; fn < 2; fn++) {
        int m = wc + fn * 16 + lr;
        int kb = wr + fm * 16 + rb;
#pragma unroll
        for (int r = 0; r < 4; r++) pk.h[r] = (bf16_t)acc[fm][fn][r];
        *(uint2*)&Fb[m][kb] = pk.u;
      }
    __syncthreads();  // Fb visible
    for (int c = threadIdx.x; c < 64 * 16; c += 256) {
      int row = c >> 4;
      uint4 v = *(uint4*)&Fb[row][col8 * 8];
      *(uint4*)&F[base + (size_t)(mt * 64 + row) * 128 + col8 * 8] = v;
      const bf16_t* hp = (const bf16_t*)&v;
#pragma unroll
      for (int e = 0; e < 8; e++) {
        float f = (float)hp[e];
        s8[e] += f;
        q8[e] += f * f;
      }
    }
  }
  int sub = threadIdx.x >> 4;
#pragma unroll
  for (int e = 0; e < 8; e++) {
    rs[(sub * 16 + col8) * 8 + e] = s8[e];
    rq[(sub * 16 + col8) * 8 + e] = q8[e];
  }
  __syncthreads();
  if (threadIdx.x < 128) {
    int k = threadIdx.x, kg = k >> 3, e = k & 7;
    float S = 0.f, Q = 0.f;
#pragma unroll
    for (int s = 0; s < 16; s++) {
      S += rs[(s * 16 + kg) * 8 + e];
      Q += rq[(s * 16 + kg) * 8 + e];
    }
    part[(size_t)bl * 256 + k] = S;
    part[(size_t)bl * 256 + 128 + k] = Q;
  }
}

// ----------- K5 (R6-validated): ss[b][0][k]=scale, ss[b][1][k]=shift
__global__ __launch_bounds__(64) void k_stats2(const float* __restrict__ part,
                                               const float* __restrict__ gamma,
                                               const float* __restrict__ beta,
                                               float* __restrict__ ss) {
  int k = blockIdx.x, b = blockIdx.y, t = threadIdx.x;
  float S = 0.f, Q = 0.f;
  for (int l = t; l < 384; l += 64) {
    S += part[(size_t)(b * 384 + l) * 256 + k];
    Q += part[(size_t)(b * 384 + l) * 256 + 128 + k];
  }
#pragma unroll
  for (int o = 32; o; o >>= 1) {
    S += __shfl_down(S, o, 64);
    Q += __shfl_down(Q, o, 64);
  }
  if (t == 0) {
    const float inv = 1.0f / 147456.0f;
    float mean = S * inv;
    float var = Q * inv - mean * mean;
    float sc = gamma[k] * rsqrtf(var + 1e-5f);
    ss[b * 256 + k] = sc;
    ss[b * 256 + 128 + k] = beta[k] - mean * sc;
  }
}

// --- K7: fused norm+relu -> conv3x3 -> relu -> conv1x1 + bias.
// Full-row tile (128oc x 384px, 8 waves of 64oc x 96px) with A (weights)
// loaded per-wave global->VGPR in fragment order (R5-validated mechanism):
// LDS carries ONLY the B slab, the dx/tap loop is barrier-free (compiler
// hoists next tap's A-loads under MFMAs), and weights ride the L1/L2 pipe
// in parallel with LDS reads. 1 barrier pair per dy. LDS 98.8 KB.
__global__ __launch_bounds__(512, 1) void k_conv(
    const bf16_t* __restrict__ Fn, const float* __restrict__ ss,
    const bf16_t* __restrict__ Wc2, const bf16_t* __restrict__ Wo2,
    const float* __restrict__ outb, float* __restrict__ out) {
  int orig = blockIdx.x;
  int wg = (orig & 7) * 96 + (orig >> 3);  // 768 % 8 == 0: bijective
  int b = wg / 384;
  int y = wg - b * 384;

  __shared__ __align__(16) char smB[98816];  // 386 rows x 256B (swizzled)

  int tid = threadIdx.x;
  int w = tid >> 6, ln = tid & 63;
  int wrh = w & 1, pxb = (w >> 1) * 96;
  int lr = ln & 15, g = ln >> 4, rb = g * 4;

  // per-thread scale/shift for the fixed staging column c8 = (tid&15)*8
  int c8 = (tid & 15) * 8;
  float scr[8], shr[8];
  {
    const float* sb = ss + b * 256;
    *(f32x4*)&scr[0] = *(const f32x4*)&sb[c8];
    *(f32x4*)&scr[4] = *(const f32x4*)&sb[c8 + 4];
    *(f32x4*)&shr[0] = *(const f32x4*)&sb[128 + c8];
    *(f32x4*)&shr[4] = *(const f32x4*)&sb[128 + c8 + 4];
  }

  f32x4 acc[4][6] = {};
  for (int dy = 0; dy < 3; dy++) {
    int yy = y + dy - 1;
    bool yok = (yy >= 0 && yy < 384);
    __syncthreads();  // prev-dy B reads done
    // ---- stage B: full row (386 px incl borders), norm+relu in regs,
    //      swizzled ds_write, zero-pad OOB
    const char* Frow = (const char*)Fn + (size_t)(b * 384 + yy) * 98304;
#pragma unroll
    for (int i = 0; i < 13; i++) {
      int s = tid + i * 512;
      if (s < 6176) {  // 386 * 16
        int px = s >> 4, c16 = (s & 15) << 4;
        int xx = px - 1;
        bf16x8 o;
        if (yok && xx >= 0 && xx < 384) {
          bf16x8 f = *(const bf16x8*)(Frow + (size_t)xx * 256 + c16);
#pragma unroll
          for (int e = 0; e < 8; e++) {
            float v = (float)f[e] * scr[e] + shr[e];
            o[e] = (bf16_t)(v > 0.f ? v : 0.f);
          }
        } else {
#pragma unroll
          for (int e = 0; e < 8; e++) o[e] = (bf16_t)0.f;
        }
        int byte = (px << 8) + c16;
        *(bf16x8*)(smB + (byte ^ ((px & 7) << 4))) = o;
      }
    }
    __syncthreads();  // B visible
    // ---- 3 taps, barrier-free: A per-wave global->VGPR fragments
#pragma unroll
    for (int dx = 0; dx < 3; dx++) {
      const bf16_t* Atap =
          Wc2 + (size_t)(dy * 3 + dx) * 16384 + wrh * 8192 + ln * 8;
      bf16x8 av[4][4];  // [kc][fm] — all static indices
#pragma unroll
      for (int kc = 0; kc < 4; kc++)
#pragma unroll
        for (int fm = 0; fm < 4; fm++)
          av[kc][fm] = *(const bf16x8*)&Atap[kc * 2048 + fm * 512];
#pragma unroll
      for (int kc = 0; kc < 4; kc++) {
        bf16x8 bv[6];
#pragma unroll
        for (int fn = 0; fn < 6; fn++) {
          int row = pxb + fn * 16 + lr + dx;
          int byte = (row << 8) + (kc << 6) + (g << 4);
          bv[fn] = *(const bf16x8*)(smB + (byte ^ ((row & 7) << 4)));
        }
#pragma unroll
        for (int fm = 0; fm < 4; fm++)
#pragma unroll
          for (int fn = 0; fn < 6; fn++)
            acc[fm][fn] = MFMA(av[kc][fm], bv[fn], acc[fm][fn]);
      }
    }
  }
  // ---- epilogue: relu(mix)->Mx (overlays B slab), 1x1 (Wo from global) + bias
  __syncthreads();  // all conv B reads done
  union {
    bf16_t hh[4];
    uint2 u;
  } pk;
#pragma unroll
  for (int fm = 0; fm < 4; fm++)
#pragma unroll
    for (int fn = 0; fn < 6; fn++) {
      int px = pxb + fn * 16 + lr;
      int mcb = wrh * 64 + fm * 16 + rb;
#pragma unroll
      for (int r = 0; r < 4; r++) {
        float v = acc[fm][fn][r];
        pk.hh[r] = (bf16_t)(v > 0.f ? v : 0.f);
      }
      int byte = (px << 8) + (mcb << 1);
      *(uint2*)(smB + (byte ^ ((px & 7) << 4))) = pk.u;
    }
  __syncthreads();  // Mx visible
  f32x4 acc2[4][6] = {};
  const bf16_t* Awo = Wo2 + wrh * 8192 + ln * 8;
#pragma unroll
  for (int kc = 0; kc < 4; kc++) {
    bf16x8 av2[4];
#pragma unroll
    for (int fm = 0; fm < 4; fm++)
      av2[fm] = *(const bf16x8*)&Awo[kc * 2048 + fm * 512];
    bf16x8 bv[6];
#pragma unroll
    for (int fn = 0; fn < 6; fn++) {
      int row = pxb + fn * 16 + lr;
      int byte = (row << 8) + (kc << 6) + (g << 4);
      bv[fn] = *(const bf16x8*)(smB + (byte ^ ((row & 7) << 4)));
    }
#pragma unroll
    for (int fm = 0; fm < 4; fm++)
#pragma unroll
      for (int fn = 0; fn < 6; fn++)
        acc2[fm][fn] = MFMA(av2[fm], bv[fn], acc2[fm][fn]);
  }
  f32x4 obv[4];
#pragma unroll
  for (int fm = 0; fm < 4; fm++)
    obv[fm] = *(const f32x4*)&outb[wrh * 64 + fm * 16 + rb];
#pragma unroll
  for (int fm = 0; fm < 4; fm++)
#pragma unroll
    for (int fn = 0; fn < 6; fn++) {
      int x = pxb + fn * 16 + lr;
#pragma unroll
      for (int r = 0; r < 4; r++) {
        int oc2 = wrh * 64 + fm * 16 + rb + r;
        out[((size_t)(b * 128 + oc2) * 384 + y) * 384 + x] =
            acc2[fm][fn][r] + obv[fm][r];
      }
    }
}

extern "C" void kernel_launch(void* const* d_in, const int* in_sizes, int n_in,
                              void* d_out, int out_size, void* d_ws,
                              size_t ws_size, hipStream_t stream) {
  const float* h = (const float*)d_in[0];
  const float* Wi = (const float*)d_in[1];
  const float* bi = (const float*)d_in[2];
  const float* Wj = (const float*)d_in[3];
  const float* bj = (const float*)d_in[4];
  const float* Wbl = (const float*)d_in[5];
  const float* gamma = (const float*)d_in[6];
  const float* beta = (const float*)d_in[7];
  const float* mw = (const float*)d_in[8];
  const float* ow = (const float*)d_in[9];
  const float* ob = (const float*)d_in[10];
  float* out = (float*)d_out;

  char* ws = (char*)d_ws;
  size_t off = 0;
  auto alloc = [&](size_t bytes) -> void* {
    void* p = ws + off;
    off = (off + bytes + 255) & ~(size_t)255;
    return p;
  };
  bf16_t* ui_b = (bf16_t*)alloc(768 * 128 * 2);
  bf16_t* vj_b = (bf16_t*)alloc(768 * 128 * 2);
  bf16_t* Wt = (bf16_t*)alloc((size_t)2097152 * 2);
  bf16_t* Wc2 = (bf16_t*)alloc((size_t)147456 * 2);
  bf16_t* Wo2 = (bf16_t*)alloc((size_t)16384 * 2);
  bf16_t* T = (bf16_t*)alloc((size_t)768 * 16384 * 2);
  bf16_t* F = (bf16_t*)alloc((size_t)2 * 384 * 384 * 128 * 2);
  float* part = (float*)alloc((size_t)768 * 256 * 4);
  float* ssb = (float*)alloc((size_t)2 * 256 * 4);

  k_lin2<<<dim3(12, 2), 256, 0, stream>>>(h, Wi, bi, Wj, bj, ui_b, vj_b);
  k_wt<<<dim3(128, 4, 4), 256, 0, stream>>>(Wbl, Wt);
  k_wc<<<(147456 + 255) / 256, 256, 0, stream>>>(mw, Wc2);
  k_wo<<<64, 256, 0, stream>>>(ow, Wo2);
  k_tgemm<<<dim3(12, 256), 256, 0, stream>>>(ui_b, Wt, T);
  k_feat<<<768, 256, 0, stream>>>(T, vj_b, F, part);
  k_stats2<<<dim3(128, 2), 64, 0, stream>>>(part, gamma, beta, ssb);
  k_conv<<<768, 512, 0, stream>>>(F, ssb, Wc2, Wo2, ob, out);
}

// Round 16
// 209.419 us; speedup vs baseline: 1.6612x; 1.6612x over previous
//
#include <hip/hip_runtime.h>
#include <hip/hip_bf16.h>
#include <stdint.h>

typedef __bf16 bf16_t;
typedef __bf16 bf16x8 __attribute__((ext_vector_type(8)));
typedef float  f32x4  __attribute__((ext_vector_type(4)));

#define MFMA(a, b, c) __builtin_amdgcn_mfma_f32_16x16x32_bf16((a), (b), (c), 0, 0, 0)

__device__ __forceinline__ void gload_lds16(const void* g, void* l) {
  __builtin_amdgcn_global_load_lds(
      (const __attribute__((address_space(1))) unsigned int*)(g),
      (__attribute__((address_space(3))) unsigned int*)(l), 16, 0, 0);
}

// ---- K1 (R13-validated): both linears as one tiled MFMA GEMM
__global__ __launch_bounds__(256) void k_lin2(
    const float* __restrict__ h, const float* __restrict__ Wi,
    const float* __restrict__ bi, const float* __restrict__ Wj,
    const float* __restrict__ bj, bf16_t* __restrict__ ui,
    bf16_t* __restrict__ vj) {
  int m0 = blockIdx.x * 64;
  int which = blockIdx.y;
  const float* W = which ? Wj : Wi;
  const float* bias = which ? bj : bi;
  bf16_t* out = which ? vj : ui;
  __shared__ bf16_t Al[64][136];   // 17408 B
  __shared__ bf16_t Bl[128][136];  // 34816 B
  int w = threadIdx.x >> 6, ln = threadIdx.x & 63;
  int wr = (w >> 1) * 32, wc = (w & 1) * 64;
  int lr = ln & 15, hi8 = (ln >> 4) * 8, rb = (ln >> 4) * 4;
  f32x4 acc[2][4] = {};
  for (int kc0 = 0; kc0 < 1024; kc0 += 128) {
    __syncthreads();  // prev chunk's MFMA reads done
    for (int c = threadIdx.x; c < 64 * 16; c += 256) {
      int row = c >> 4, col = (c & 15) * 8;
      const float* src = &h[(size_t)(m0 + row) * 1024 + kc0 + col];
      f32x4 a = *(const f32x4*)src, b2 = *(const f32x4*)(src + 4);
      bf16x8 o;
#pragma unroll
      for (int e = 0; e < 4; e++) {
        o[e] = (bf16_t)a[e];
        o[e + 4] = (bf16_t)b2[e];
      }
      *(bf16x8*)&Al[row][col] = o;
    }
    for (int c = threadIdx.x; c < 128 * 16; c += 256) {
      int row = c >> 4, col = (c & 15) * 8;
      const float* src = &W[(size_t)row * 1024 + kc0 + col];
      f32x4 a = *(const f32x4*)src, b2 = *(const f32x4*)(src + 4);
      bf16x8 o;
#pragma unroll
      for (int e = 0; e < 4; e++) {
        o[e] = (bf16_t)a[e];
        o[e + 4] = (bf16_t)b2[e];
      }
      *(bf16x8*)&Bl[row][col] = o;
    }
    __syncthreads();  // tiles visible
#pragma unroll
    for (int kc = 0; kc < 128; kc += 32) {
      bf16x8 a0 = *(bf16x8*)&Al[wr + lr][kc + hi8];
      bf16x8 a1 = *(bf16x8*)&Al[wr + 16 + lr][kc + hi8];
#pragma unroll
      for (int fn = 0; fn < 4; fn++) {
        bf16x8 bv = *(bf16x8*)&Bl[wc + fn * 16 + lr][kc + hi8];
        acc[0][fn] = MFMA(a0, bv, acc[0][fn]);
        acc[1][fn] = MFMA(a1, bv, acc[1][fn]);
      }
    }
  }
#pragma unroll
  for (int fm = 0; fm < 2; fm++)
#pragma unroll
    for (int fn = 0; fn < 4; fn++) {
      int col = wc + fn * 16 + lr;
      float bb = bias[col];
#pragma unroll
      for (int r = 0; r < 4; r++) {
        int row = m0 + wr + fm * 16 + rb + r;
        out[row * 128 + col] = (bf16_t)(acc[fm][fn][r] + bb);
      }
    }
}

// ------------------------------------------------- K2a: W[i][j][k]->Wt[k][j][i]
__global__ __launch_bounds__(256) void k_wt(const float* __restrict__ W,
                                            bf16_t* __restrict__ Wt) {
  int j = blockIdx.x;
  int i0 = blockIdx.y * 32, k0 = blockIdx.z * 32;
  __shared__ float tile[32][33];
  int tx = threadIdx.x & 31, ty = threadIdx.x >> 5;  // ty 0..7
#pragma unroll
  for (int r = 0; r < 4; r++) {
    int ii = ty + r * 8;
    tile[ii][tx] = W[(size_t)(i0 + ii) * 16384 + j * 128 + (k0 + tx)];
  }
  __syncthreads();
#pragma unroll
  for (int r = 0; r < 4; r++) {
    int kk = ty + r * 8;
    Wt[(size_t)(k0 + kk) * 16384 + j * 128 + (i0 + tx)] = (bf16_t)tile[tx][kk];
  }
}

// -------- K2b (R3-validated): mix_w -> Wc2[tap][wrh][kc][fm][ln][e]
__global__ __launch_bounds__(256) void k_wc(const float* __restrict__ mw,
                                            bf16_t* __restrict__ Wc2) {
  int idx = blockIdx.x * 256 + threadIdx.x;
  if (idx < 147456) {
    int e = idx & 7, ln = (idx >> 3) & 63, fm = (idx >> 9) & 3;
    int kc = (idx >> 11) & 3, wrh = (idx >> 13) & 1, tap = idx >> 14;
    int oc = wrh * 64 + fm * 16 + (ln & 15);
    int ic = kc * 32 + (ln >> 4) * 8 + e;
    Wc2[idx] = (bf16_t)mw[oc * 1152 + ic * 9 + tap];
  }
}

// -------- K2c (R3-validated): out_w -> Wo2[wrh][kc][fm][ln][e]
__global__ __launch_bounds__(256) void k_wo(const float* __restrict__ ow,
                                            bf16_t* __restrict__ Wo2) {
  int idx = blockIdx.x * 256 + threadIdx.x;
  if (idx < 16384) {
    int e = idx & 7, ln = (idx >> 3) & 63, fm = (idx >> 9) & 3;
    int kc = (idx >> 11) & 3, wrh = (idx >> 13) & 1;
    int oc2 = wrh * 64 + fm * 16 + (ln & 15);
    int mc = kc * 32 + (ln >> 4) * 8 + e;
    Wo2[idx] = (bf16_t)ow[oc2 * 128 + mc];
  }
}

// ------------------- K3: t[bl][k*128+j] = sum_i ui[bl][i] * Wt[k][j][i]  (GEMM)
__global__ __launch_bounds__(256) void k_tgemm(const bf16_t* __restrict__ A,
                                               const bf16_t* __restrict__ Bt,
                                               bf16_t* __restrict__ T) {
  int m0 = blockIdx.x * 64;  // bl
  int n0 = blockIdx.y * 64;  // (k,j)
  __shared__ bf16_t Al[64][136], Bl[64][136];
  for (int c = threadIdx.x; c < 64 * 16; c += 256) {
    int row = c >> 4, col = (c & 15) * 8;
    *(uint4*)&Al[row][col] = *(const uint4*)&A[(size_t)(m0 + row) * 128 + col];
    *(uint4*)&Bl[row][col] = *(const uint4*)&Bt[(size_t)(n0 + row) * 128 + col];
  }
  __syncthreads();
  int w = threadIdx.x >> 6, ln = threadIdx.x & 63;
  int wr = (w >> 1) * 32, wc = (w & 1) * 32;
  int lr = ln & 15, hi8 = (ln >> 4) * 8, rb = (ln >> 4) * 4;
  f32x4 acc[2][2] = {};
#pragma unroll
  for (int kc = 0; kc < 128; kc += 32) {
    bf16x8 a0 = *(bf16x8*)&Al[wr + lr][kc + hi8];
    bf16x8 a1 = *(bf16x8*)&Al[wr + 16 + lr][kc + hi8];
    bf16x8 b0 = *(bf16x8*)&Bl[wc + lr][kc + hi8];
    bf16x8 b1 = *(bf16x8*)&Bl[wc + 16 + lr][kc + hi8];
    acc[0][0] = MFMA(a0, b0, acc[0][0]);
    acc[0][1] = MFMA(a0, b1, acc[0][1]);
    acc[1][0] = MFMA(a1, b0, acc[1][0]);
    acc[1][1] = MFMA(a1, b1, acc[1][1]);
  }
#pragma unroll
  for (int fm = 0; fm < 2; fm++)
#pragma unroll
    for (int fn = 0; fn < 2; fn++) {
      int col = n0 + wc + fn * 16 + lr;
#pragma unroll
      for (int r = 0; r < 4; r++) {
        int row = m0 + wr + fm * 16 + rb + r;
        T[(size_t)row * 16384 + col] = (bf16_t)acc[fm][fn][r];
      }
    }
}

// ------- K4 (R6-validated): feat + fused deterministic norm partial sums
__global__ __launch_bounds__(256) void k_feat(const bf16_t* __restrict__ T,
                                              const bf16_t* __restrict__ Vb,
                                              bf16_t* __restrict__ F,
                                              float* __restrict__ part) {
  int bl = blockIdx.x;
  int b = bl / 384;
  __shared__ __align__(16) char sm[52224];
  bf16_t (*Tl)[136] = (bf16_t(*)[136])(sm);          // 34816
  bf16_t (*Fb)[136] = (bf16_t(*)[136])(sm + 34816);  // 17408
  float* rs = (float*)(sm);                          // overlay after MFMAs
  float* rq = (float*)(sm + 8192);
  const bf16_t* tsrc = T + (size_t)bl * 16384;
  for (int c = threadIdx.x; c < 128 * 16; c += 256) {
    int row = c >> 4, col = (c & 15) * 8;
    *(uint4*)&Tl[row][col] = *(const uint4*)&tsrc[row * 128 + col];
  }
  __syncthreads();
  int w = threadIdx.x >> 6, ln = threadIdx.x & 63;
  int wr = (w >> 1) * 64, wc = (w & 1) * 32;
  int lr = ln & 15, g = ln >> 4, hi8 = g * 8, rb = g * 4;
  size_t base = (size_t)bl * 384 * 128;
  float s8[8] = {}, q8[8] = {};
  int col8 = threadIdx.x & 15;
  for (int mt = 0; mt < 6; mt++) {
    bf16x8 vf[2][4];
#pragma unroll
    for (int fn = 0; fn < 2; fn++)
#pragma unroll
      for (int kc = 0; kc < 4; kc++) {
        int m = mt * 64 + wc + fn * 16 + lr;
        vf[fn][kc] = *(const bf16x8*)&Vb[(size_t)(b * 384 + m) * 128 +
                                         kc * 32 + hi8];
      }
    f32x4 acc[4][2] = {};
#pragma unroll
    for (int kc = 0; kc < 4; kc++) {
#pragma unroll
      for (int fm = 0; fm < 4; fm++) {
        bf16x8 av = *(bf16x8*)&Tl[wr + fm * 16 + lr][kc * 32 + hi8];
        acc[fm][0] = MFMA(av, vf[0][kc], acc[fm][0]);
        acc[fm][1] = MFMA(av, vf[1][kc], acc[fm][1]);
      }
    }
    __syncthreads();  // prev copy-out done: Fb overwrite safe
    union {
      bf16_t h[4];
      uint2 u;
    } pk;
#pragma unroll
    for (int fm = 0; fm < 4; fm++)
#pragma unroll
      for (int fn = 0; fn < 2; fn++) {
        int m = wc + fn * 16 + lr;
        int kb = wr + fm * 16 + rb;
#pragma unroll
        for (int r = 0; r < 4; r++) pk.h[r] = (bf16_t)acc[fm][fn][r];
        *(uint2*)&Fb[m][kb] = pk.u;
      }
    __syncthreads();  // Fb visible
    for (int c = threadIdx.x; c < 64 * 16; c += 256) {
      int row = c >> 4;
      uint4 v = *(uint4*)&Fb[row][col8 * 8];
      *(uint4*)&F[base + (size_t)(mt * 64 + row) * 128 + col8 * 8] = v;
      const bf16_t* hp = (const bf16_t*)&v;
#pragma unroll
      for (int e = 0; e < 8; e++) {
        float f = (float)hp[e];
        s8[e] += f;
        q8[e] += f * f;
      }
    }
  }
  int sub = threadIdx.x >> 4;
#pragma unroll
  for (int e = 0; e < 8; e++) {
    rs[(sub * 16 + col8) * 8 + e] = s8[e];
    rq[(sub * 16 + col8) * 8 + e] = q8[e];
  }
  __syncthreads();
  if (threadIdx.x < 128) {
    int k = threadIdx.x, kg = k >> 3, e = k & 7;
    float S = 0.f, Q = 0.f;
#pragma unroll
    for (int s = 0; s < 16; s++) {
      S += rs[(s * 16 + kg) * 8 + e];
      Q += rq[(s * 16 + kg) * 8 + e];
    }
    part[(size_t)bl * 256 + k] = S;
    part[(size_t)bl * 256 + 128 + k] = Q;
  }
}

// ----------- K5 (R6-validated): ss[b][0][k]=scale, ss[b][1][k]=shift
__global__ __launch_bounds__(64) void k_stats2(const float* __restrict__ part,
                                               const float* __restrict__ gamma,
                                               const float* __restrict__ beta,
                                               float* __restrict__ ss) {
  int k = blockIdx.x, b = blockIdx.y, t = threadIdx.x;
  float S = 0.f, Q = 0.f;
  for (int l = t; l < 384; l += 64) {
    S += part[(size_t)(b * 384 + l) * 256 + k];
    Q += part[(size_t)(b * 384 + l) * 256 + 128 + k];
  }
#pragma unroll
  for (int o = 32; o; o >>= 1) {
    S += __shfl_down(S, o, 64);
    Q += __shfl_down(Q, o, 64);
  }
  if (t == 0) {
    const float inv = 1.0f / 147456.0f;
    float mean = S * inv;
    float var = Q * inv - mean * mean;
    float sc = gamma[k] * rsqrtf(var + 1e-5f);
    ss[b * 256 + k] = sc;
    ss[b * 256 + 128 + k] = beta[k] - mean * sc;
  }
}

// --- K7 (R12-validated, best-known): fused norm+relu -> conv3x3 -> relu ->
// conv1x1 + bias. No setprio (measured -4us regression in R13).
__global__ __launch_bounds__(256, 2) void k_conv(
    const bf16_t* __restrict__ Fn, const float* __restrict__ ss,
    const bf16_t* __restrict__ Wc2, const bf16_t* __restrict__ Wo2,
    const float* __restrict__ outb, float* __restrict__ out) {
  int orig = blockIdx.x;
  int wg = (orig & 7) * 288 + (orig >> 3);  // 2304 % 8 == 0: bijective
  int xt = wg % 3;
  int t1 = wg / 3;
  int b = t1 / 384;
  int y = t1 - b * 384;
  int x0 = xt * 128;

  __shared__ __align__(16) char sm[66048];
  char* smB = sm + 32768;  // 130 rows x 256B (swizzled); epilogue: Mx 128x256B

  int tid = threadIdx.x;
  int w = tid >> 6, ln = tid & 63;
  int wrh = w >> 1, pxb = (w & 1) * 64;
  int lr = ln & 15, g = ln >> 4, rb = g * 4;

  // per-thread scale/shift for the fixed staging column c8 = (tid&15)*8
  int c8 = (tid & 15) * 8;
  float scr[8], shr[8];
  {
    const float* sb = ss + b * 256;
    *(f32x4*)&scr[0] = *(const f32x4*)&sb[c8];
    *(f32x4*)&scr[4] = *(const f32x4*)&sb[c8 + 4];
    *(f32x4*)&shr[0] = *(const f32x4*)&sb[128 + c8];
    *(f32x4*)&shr[4] = *(const f32x4*)&sb[128 + c8 + 4];
  }

  f32x4 acc[4][4] = {};
  for (int dy = 0; dy < 3; dy++) {
    int yy = y + dy - 1;
    bool yok = (yy >= 0 && yy < 384);
    __syncthreads();  // prev-dy A/B reads done
    // ---- stage B: load raw F, norm+relu in regs, swizzled ds_write, 0-pad
    const char* Frow = (const char*)Fn + (size_t)(b * 384 + yy) * 98304;
#pragma unroll
    for (int i = 0; i < 9; i++) {
      int s = tid + i * 256;
      if (s < 2080) {
        int px = s >> 4, c16 = (s & 15) << 4;
        int xx = x0 - 1 + px;
        bf16x8 o;
        if (yok && xx >= 0 && xx < 384) {
          bf16x8 f = *(const bf16x8*)(Frow + (size_t)xx * 256 + c16);
#pragma unroll
          for (int e = 0; e < 8; e++) {
            float v = (float)f[e] * scr[e] + shr[e];
            o[e] = (bf16_t)(v > 0.f ? v : 0.f);
          }
        } else {
#pragma unroll
          for (int e = 0; e < 8; e++) o[e] = (bf16_t)0.f;
        }
        int byte = (px << 8) + c16;
        *(bf16x8*)(smB + (byte ^ ((px & 7) << 4))) = o;
      }
    }
#pragma unroll
    for (int dx = 0; dx < 3; dx++) {
      if (dx) __syncthreads();  // prev tap A reads done
      const char* WcTap = (const char*)Wc2 + (size_t)(dy * 3 + dx) * 32768;
#pragma unroll
      for (int i = 0; i < 8; i++) {
        int o4 = w * 8192 + i * 1024 + ln * 16;
        gload_lds16(WcTap + o4, sm + o4);
      }
      __syncthreads();  // drains vmcnt+lgkm: A and B ready
#pragma unroll
      for (int kc = 0; kc < 4; kc++) {
        bf16x8 av[4], bv[4];
#pragma unroll
        for (int fn = 0; fn < 4; fn++) {
          int row = pxb + fn * 16 + lr + dx;
          int byte = (row << 8) + (kc << 6) + (g << 4);
          bv[fn] = *(const bf16x8*)(smB + (byte ^ ((row & 7) << 4)));
        }
#pragma unroll
        for (int fm = 0; fm < 4; fm++)
          av[fm] = *(const bf16x8*)(sm + wrh * 16384 + kc * 4096 + fm * 1024 +
                                    ln * 16);
#pragma unroll
        for (int fm = 0; fm < 4; fm++)
#pragma unroll
          for (int fn = 0; fn < 4; fn++)
            acc[fm][fn] = MFMA(av[fm], bv[fn], acc[fm][fn]);
      }
    }
  }
  // ---- epilogue: stage Wo2 (A region), relu(mix)->Mx (B region), 1x1 + bias
  __syncthreads();  // all conv reads done
#pragma unroll
  for (int i = 0; i < 8; i++) {
    int o4 = w * 8192 + i * 1024 + ln * 16;
    gload_lds16((const char*)Wo2 + o4, sm + o4);
  }
  union {
    bf16_t hh[4];
    uint2 u;
  } pk;
#pragma unroll
  for (int fm = 0; fm < 4; fm++)
#pragma unroll
    for (int fn = 0; fn < 4; fn++) {
      int px = pxb + fn * 16 + lr;
      int mcb = wrh * 64 + fm * 16 + rb;
#pragma unroll
      for (int r = 0; r < 4; r++) {
        float v = acc[fm][fn][r];
        pk.hh[r] = (bf16_t)(v > 0.f ? v : 0.f);
      }
      int byte = (px << 8) + (mcb << 1);
      *(uint2*)(smB + (byte ^ ((px & 7) << 4))) = pk.u;
    }
  __syncthreads();  // Wo2 + Mx visible
  f32x4 acc2[4][4] = {};
#pragma unroll
  for (int kc = 0; kc < 4; kc++) {
    bf16x8 av[4], bv[4];
#pragma unroll
    for (int fn = 0; fn < 4; fn++) {
      int row = pxb + fn * 16 + lr;
      int byte = (row << 8) + (kc << 6) + (g << 4);
      bv[fn] = *(const bf16x8*)(smB + (byte ^ ((row & 7) << 4)));
    }
#pragma unroll
    for (int fm = 0; fm < 4; fm++)
      av[fm] = *(const bf16x8*)(sm + wrh * 16384 + kc * 4096 + fm * 1024 +
                                ln * 16);
#pragma unroll
    for (int fm = 0; fm < 4; fm++)
#pragma unroll
      for (int fn = 0; fn < 4; fn++)
        acc2[fm][fn] = MFMA(av[fm], bv[fn], acc2[fm][fn]);
  }
  f32x4 obv[4];
#pragma unroll
  for (int fm = 0; fm < 4; fm++)
    obv[fm] = *(const f32x4*)&outb[wrh * 64 + fm * 16 + rb];
#pragma unroll
  for (int fm = 0; fm < 4; fm++)
#pragma unroll
    for (int fn = 0; fn < 4; fn++) {
      int x = x0 + pxb + fn * 16 + lr;
#pragma unroll
      for (int r = 0; r < 4; r++) {
        int oc2 = wrh * 64 + fm * 16 + rb + r;
        out[((size_t)(b * 128 + oc2) * 384 + y) * 384 + x] =
            acc2[fm][fn][r] + obv[fm][r];
      }
    }
}

extern "C" void kernel_launch(void* const* d_in, const int* in_sizes, int n_in,
                              void* d_out, int out_size, void* d_ws,
                              size_t ws_size, hipStream_t stream) {
  const float* h = (const float*)d_in[0];
  const float* Wi = (const float*)d_in[1];
  const float* bi = (const float*)d_in[2];
  const float* Wj = (const float*)d_in[3];
  const float* bj = (const float*)d_in[4];
  const float* Wbl = (const float*)d_in[5];
  const float* gamma = (const float*)d_in[6];
  const float* beta = (const float*)d_in[7];
  const float* mw = (const float*)d_in[8];
  const float* ow = (const float*)d_in[9];
  const float* ob = (const float*)d_in[10];
  float* out = (float*)d_out;

  char* ws = (char*)d_ws;
  size_t off = 0;
  auto alloc = [&](size_t bytes) -> void* {
    void* p = ws + off;
    off = (off + bytes + 255) & ~(size_t)255;
    return p;
  };
  bf16_t* ui_b = (bf16_t*)alloc(768 * 128 * 2);
  bf16_t* vj_b = (bf16_t*)alloc(768 * 128 * 2);
  bf16_t* Wt = (bf16_t*)alloc((size_t)2097152 * 2);
  bf16_t* Wc2 = (bf16_t*)alloc((size_t)147456 * 2);
  bf16_t* Wo2 = (bf16_t*)alloc((size_t)16384 * 2);
  bf16_t* T = (bf16_t*)alloc((size_t)768 * 16384 * 2);
  bf16_t* F = (bf16_t*)alloc((size_t)2 * 384 * 384 * 128 * 2);
  float* part = (float*)alloc((size_t)768 * 256 * 4);
  float* ssb = (float*)alloc((size_t)2 * 256 * 4);

  k_lin2<<<dim3(12, 2), 256, 0, stream>>>(h, Wi, bi, Wj, bj, ui_b, vj_b);
  k_wt<<<dim3(128, 4, 4), 256, 0, stream>>>(Wbl, Wt);
  k_wc<<<(147456 + 255) / 256, 256, 0, stream>>>(mw, Wc2);
  k_wo<<<64, 256, 0, stream>>>(ow, Wo2);
  k_tgemm<<<dim3(12, 256), 256, 0, stream>>>(ui_b, Wt, T);
  k_feat<<<768, 256, 0, stream>>>(T, vj_b, F, part);
  k_stats2<<<dim3(128, 2), 64, 0, stream>>>(part, gamma, beta, ssb);
  k_conv<<<2304, 256, 0, stream>>>(F, ssb, Wc2, Wo2, ob, out);
}